// Round 5
// baseline (1310.512 us; speedup 1.0000x reference)
//
#include <hip/hip_runtime.h>

#define D_IN 128
#define D_OUT 64
#define NS 1024        // row slices; R = ceil(n/NS) rows per slice (98 for n=100k)
#define NBLK 256       // blocks for hist/part (256 = 8 XCDs x 32)
#define CSHIFT 18
#define CMASK 0x3FFFFu // 18-bit col field (n < 262144)

// --- bf16 helpers ----------------------------------------------------------
__device__ inline float u2f(unsigned int u) {
    union { unsigned int i; float f; } v; v.i = u; return v.f;
}
__device__ inline float bf2f(unsigned short u) { return u2f(((unsigned int)u) << 16); }
__device__ inline unsigned short f2bf(float f) {
    union { float f; unsigned int i; } v; v.f = f;
    unsigned int r = v.i + 0x7fffu + ((v.i >> 16) & 1u);
    return (unsigned short)(r >> 16);
}
// slice = rw / R via magic multiply; exact since rw*(magic*R - 2^35) < 2^35
__device__ inline int slice_of(int rw, unsigned int magic) {
    return (int)(((unsigned long long)(unsigned int)rw * magic) >> 35);
}
// chunk id: keep adjacent edge-chunks (and their pk ranges) on the same XCD
__device__ inline int chunk_id() {
    return (blockIdx.x & 7) * (NBLK / 8) + (blockIdx.x >> 3);
}

// ---------------------------------------------------------------------------
// K1: per-chunk histogram over NS slices. bcnt layout slice-major:
//     bcnt[s*NBLK + cid]. No global deg atomics (deg comes from k_deg).
// ---------------------------------------------------------------------------
__global__ __launch_bounds__(256) void k_hist(
    const int* __restrict__ row, unsigned int* __restrict__ bcnt,
    int E, unsigned int magic) {
    __shared__ unsigned int cnt[NS];
    for (int t = threadIdx.x; t < NS; t += 256) cnt[t] = 0;
    __syncthreads();
    const int cid = chunk_id();
    const int chunk = (E + NBLK - 1) / NBLK;
    const int lo = cid * chunk, hi = min(E, lo + chunk);
    for (int e = lo + threadIdx.x; e < hi; e += 256) {
        int rw = __builtin_nontemporal_load(&row[e]);
        atomicAdd(&cnt[slice_of(rw, magic)], 1u);
    }
    __syncthreads();
    for (int t = threadIdx.x; t < NS; t += 256)
        bcnt[t * NBLK + cid] = cnt[t];
}

// ---------------------------------------------------------------------------
// K2: exclusive scan of bcnt[NS*NBLK] in place (one WG, 1024 thr x 256 each).
// ---------------------------------------------------------------------------
__global__ __launch_bounds__(1024) void k_scanb(unsigned int* __restrict__ bcnt) {
    __shared__ unsigned int tsum[1024];
    const int t = threadIdx.x;
    const int PER = NS * NBLK / 1024;  // 256
    const int base = t * PER;
    unsigned int s = 0;
#pragma unroll 4
    for (int k = 0; k < PER; ++k) s += bcnt[base + k];
    tsum[t] = s;
    __syncthreads();
    for (int off = 1; off < 1024; off <<= 1) {
        unsigned int u = (t >= off) ? tsum[t - off] : 0;
        __syncthreads();
        tsum[t] += u;
        __syncthreads();
    }
    unsigned int run = tsum[t] - s;
#pragma unroll 4
    for (int k = 0; k < PER; ++k) {
        unsigned int v = bcnt[base + k];
        bcnt[base + k] = run;
        run += v;
    }
}

// ---------------------------------------------------------------------------
// K3: partition edges into slice-contiguous packed words:
//     pk[pos] = (rowLocal << 18) | col.  Dense per-(chunk,slice) ranges ->
//     near-1x write amplification.
// ---------------------------------------------------------------------------
__global__ __launch_bounds__(256) void k_part(
    const int* __restrict__ row, const int* __restrict__ col,
    const unsigned int* __restrict__ bcnt, unsigned int* __restrict__ pk,
    int E, unsigned int magic, int R) {
    __shared__ unsigned int cur[NS];
    const int cid = chunk_id();
    for (int t = threadIdx.x; t < NS; t += 256)
        cur[t] = bcnt[t * NBLK + cid];
    __syncthreads();
    const int chunk = (E + NBLK - 1) / NBLK;
    const int lo = cid * chunk, hi = min(E, lo + chunk);
    for (int e = lo + threadIdx.x; e < hi; e += 256) {
        int rw = __builtin_nontemporal_load(&row[e]);
        int cw = __builtin_nontemporal_load(&col[e]);
        int s = slice_of(rw, magic);
        unsigned int pos = atomicAdd(&cur[s], 1u);
        pk[pos] = ((unsigned int)(rw - s * R) << CSHIFT) | (unsigned int)cw;
    }
}

// ---------------------------------------------------------------------------
// K4: per-slice degree via LDS histogram -> dinv written SEQUENTIALLY.
// ---------------------------------------------------------------------------
__global__ __launch_bounds__(256) void k_deg(
    const unsigned int* __restrict__ pk, const unsigned int* __restrict__ bcnt,
    float* __restrict__ dinv, int n, int E, int R) {
    __shared__ unsigned int cnt[128];  // R <= 128
    const int s = blockIdx.x;
    const int lo = s * R;
    for (int t = threadIdx.x; t < R; t += 256) cnt[t] = 0;
    __syncthreads();
    const unsigned int beg = bcnt[s * NBLK];
    const unsigned int end = (s + 1 < NS) ? bcnt[(s + 1) * NBLK] : (unsigned int)E;
    for (unsigned int i = beg + threadIdx.x; i < end; i += 256)
        atomicAdd(&cnt[__builtin_nontemporal_load(&pk[i]) >> CSHIFT], 1u);
    __syncthreads();
    for (int t = threadIdx.x; t < R && lo + t < n; t += 256)
        dinv[lo + t] = rsqrtf((float)(cnt[t] + 1u));
}

// ---------------------------------------------------------------------------
// GEMM: h[i][:] = bf16( dinv[i] * (x[i] @ W) ), 4 rows per wave.
// ---------------------------------------------------------------------------
__global__ __launch_bounds__(256) void k_gemm(
    const float* __restrict__ x, const float* __restrict__ W,
    const float* __restrict__ dinv, unsigned short* __restrict__ h, int n) {
    __shared__ float Ws[D_IN * D_OUT];
    __shared__ float xs[4][4][D_IN];
    for (int idx = threadIdx.x; idx < D_IN * D_OUT; idx += 256)
        Ws[idx] = W[idx];
    __syncthreads();

    const int wave = threadIdx.x >> 6;
    const int lane = threadIdx.x & 63;
    float* xw = &xs[wave][0][0];

    for (int i0 = (blockIdx.x * 4 + wave) * 4; i0 < n; i0 += gridDim.x * 16) {
#pragma unroll
        for (int r = 0; r < 4; ++r) {
            int i = min(i0 + r, n - 1);
            *(float2*)&xw[r * D_IN + lane * 2] =
                *(const float2*)&x[(size_t)i * D_IN + lane * 2];
        }
        float a0 = 0.f, a1 = 0.f, a2 = 0.f, a3 = 0.f;
#pragma unroll
        for (int k4 = 0; k4 < D_IN; k4 += 4) {
            float4 x0 = *(float4*)&xw[0 * D_IN + k4];
            float4 x1 = *(float4*)&xw[1 * D_IN + k4];
            float4 x2 = *(float4*)&xw[2 * D_IN + k4];
            float4 x3 = *(float4*)&xw[3 * D_IN + k4];
#pragma unroll
            for (int u = 0; u < 4; ++u) {
                float wv = Ws[(k4 + u) * D_OUT + lane];
                a0 = fmaf((&x0.x)[u], wv, a0);
                a1 = fmaf((&x1.x)[u], wv, a1);
                a2 = fmaf((&x2.x)[u], wv, a2);
                a3 = fmaf((&x3.x)[u], wv, a3);
            }
        }
        int nr = min(4, n - i0);
        if (nr == 4) {
            h[(size_t)(i0 + 0) * D_OUT + lane] = f2bf(dinv[i0 + 0] * a0);
            h[(size_t)(i0 + 1) * D_OUT + lane] = f2bf(dinv[i0 + 1] * a1);
            h[(size_t)(i0 + 2) * D_OUT + lane] = f2bf(dinv[i0 + 2] * a2);
            h[(size_t)(i0 + 3) * D_OUT + lane] = f2bf(dinv[i0 + 3] * a3);
        } else {
            for (int r = 0; r < nr; ++r) {
                float a = (r == 0) ? a0 : (r == 1) ? a1 : (r == 2) ? a2 : a3;
                h[(size_t)(i0 + r) * D_OUT + lane] = f2bf(dinv[i0 + r] * a);
            }
        }
    }
}

// ---------------------------------------------------------------------------
// K5: push-aggregation, one WG per slice. LDS fp32 accumulator acc[R][64].
//     Per edge: 64 lanes gather h[col][:] (coalesced 128B) and ds_add_f32
//     into acc[rowLocal][:] (lane-consecutive -> conflict-free).
//     Epilogue: + self-term, *dinv, +b, relu, sequential stores.
// ---------------------------------------------------------------------------
__global__ __launch_bounds__(256) void k_aggr(
    const unsigned short* __restrict__ h, const unsigned int* __restrict__ pk,
    const unsigned int* __restrict__ bcnt, const float* __restrict__ dinv,
    const float* __restrict__ bias, float* __restrict__ out,
    int n, int E, int R) {
    extern __shared__ float acc[];  // R * 64 floats
    const int s = blockIdx.x, lo = s * R;
    const int wave = threadIdx.x >> 6, lane = threadIdx.x & 63;

    for (int t = threadIdx.x; t < R * D_OUT; t += 256) acc[t] = 0.f;
    __syncthreads();

    const int beg = (int)bcnt[s * NBLK];
    const int end = (s + 1 < NS) ? (int)bcnt[(s + 1) * NBLK] : E;
    // contiguous per-wave split of the slice's edge range
    const int per = (end - beg + 3) >> 2;
    const int wbeg = beg + wave * per;
    const int wend = min(end, wbeg + per);

    int base = wbeg;
    for (; base + 64 <= wend; base += 64) {
        unsigned int p = __builtin_nontemporal_load(&pk[base + lane]);
#pragma unroll 16
        for (int j = 0; j < 64; ++j) {
            unsigned int pj = __shfl(p, j);
            int rl = pj >> CSHIFT;
            int c  = pj & CMASK;
            float v = bf2f(h[(size_t)c * D_OUT + lane]);
            atomicAdd(&acc[rl * D_OUT + lane], v);
        }
    }
    const int rem = wend - base;
    if (rem > 0) {
        unsigned int p = __builtin_nontemporal_load(&pk[base + ((lane < rem) ? lane : 0)]);
        for (int j = 0; j < rem; ++j) {
            unsigned int pj = __shfl(p, j);
            int rl = pj >> CSHIFT;
            int c  = pj & CMASK;
            float v = bf2f(h[(size_t)c * D_OUT + lane]);
            atomicAdd(&acc[rl * D_OUT + lane], v);
        }
    }
    __syncthreads();

    for (int q = wave; q < R && lo + q < n; q += 4) {
        float a = acc[q * D_OUT + lane] + bf2f(h[(size_t)(lo + q) * D_OUT + lane]);
        float r = fmaxf(fmaf(dinv[lo + q], a, bias[lane]), 0.f);
        __builtin_nontemporal_store(r, &out[(size_t)(lo + q) * D_OUT + lane]);
    }
}

extern "C" void kernel_launch(void* const* d_in, const int* in_sizes, int n_in,
                              void* d_out, int out_size, void* d_ws, size_t ws_size,
                              hipStream_t stream) {
    const float* x  = (const float*)d_in[0];
    const int*   ei = (const int*)d_in[1];   // [2][E] int32: row=targets, col=sources
    const float* W  = (const float*)d_in[2];
    const float* b  = (const float*)d_in[3];
    const int n = in_sizes[0] / D_IN;   // 100000
    const int E = in_sizes[1] / 2;      // 3200000
    const int* row = ei;
    const int* col = ei + E;

    // workspace: h 12.8MB | pk 12.8MB | dinv 0.4MB | bcnt 1MB  (~27MB)
    char* basep = (char*)d_ws;
    size_t off = 0;
    auto alloc = [&](size_t bytes) { char* p = basep + off; off += (bytes + 63) & ~(size_t)63; return p; };
    unsigned short* h    = (unsigned short*)alloc((size_t)n * D_OUT * 2);
    unsigned int*   pk   = (unsigned int*)alloc((size_t)E * 4);
    float*          dinv = (float*)alloc((size_t)n * 4);
    unsigned int*   bcnt = (unsigned int*)alloc((size_t)NS * NBLK * 4);

    const int R = (n + NS - 1) / NS;            // 98 (<=128, fits LDS + 14-bit field)
    const int NSW = (n + R - 1) / R;            // 1021 worker slices
    const unsigned int magic = (unsigned int)(((1ULL << 35) + R - 1) / R);

    k_hist<<<NBLK, 256, 0, stream>>>(row, bcnt, E, magic);
    k_scanb<<<1, 1024, 0, stream>>>(bcnt);
    k_part<<<NBLK, 256, 0, stream>>>(row, col, bcnt, pk, E, magic, R);
    k_deg<<<NSW, 256, 0, stream>>>(pk, bcnt, dinv, n, E, R);
    k_gemm<<<2048, 256, 0, stream>>>(x, W, dinv, h, n);
    k_aggr<<<NSW, 256, R * D_OUT * 4, stream>>>(h, pk, bcnt, dinv, b, (float*)d_out, n, E, R);
}

// Round 6
// 611.215 us; speedup vs baseline: 2.1441x; 2.1441x over previous
//
#include <hip/hip_runtime.h>

#define D_IN 128
#define D_OUT 64
#define NS 1024         // fine row slices; R = ceil(n/NS) rows/slice (98 @ n=100k)
#define CH 12288        // edges per k_part block (48 KB LDS buffer)
#define ACH 4096        // edges per k_aggr chunk (one chunk in practice: ~3.1K)
#define CSHIFT 17
#define CMASK 0x1FFFFu  // 17-bit col (n < 131072), rowLocal in bits 17+ (<128)

typedef unsigned int u32;

// --- bf16 helpers ----------------------------------------------------------
__device__ inline float u2f(u32 u) {
    union { u32 i; float f; } v; v.i = u; return v.f;
}
__device__ inline float bf2f(unsigned short u) { return u2f(((u32)u) << 16); }
__device__ inline unsigned short f2bf(float f) {
    union { float f; u32 i; } v; v.f = f;
    u32 r = v.i + 0x7fffu + ((v.i >> 16) & 1u);
    return (unsigned short)(r >> 16);
}
// slice = rw / R via magic multiply (exact: rw < 2^17, delta*rw < 2^35)
__device__ inline int slice_of(int rw, u32 magic) {
    return (int)(((unsigned long long)(u32)rw * magic) >> 35);
}

// ---------------------------------------------------------------------------
// K1: per-slice edge totals. LDS histogram, one global atomicAdd per
//     (block,slice) — values ~12-50, 4 KB target, cheap.
// ---------------------------------------------------------------------------
__global__ __launch_bounds__(256) void k_hist(
    const int* __restrict__ row, u32* __restrict__ stot, int E, u32 magic) {
    __shared__ u32 cnt[NS];
    for (int t = threadIdx.x; t < NS; t += 256) cnt[t] = 0;
    __syncthreads();
    const int stride = gridDim.x * 256;
    for (int e = blockIdx.x * 256 + threadIdx.x; e < E; e += stride)
        atomicAdd(&cnt[slice_of(__builtin_nontemporal_load(&row[e]), magic)], 1u);
    __syncthreads();
    for (int t = threadIdx.x; t < NS; t += 256) {
        u32 c = cnt[t];
        if (c) atomicAdd(&stot[t], c);
    }
}

// ---------------------------------------------------------------------------
// K2: exclusive scan of stot[1024] -> sstart[1025]; init gcur = sstart.
// ---------------------------------------------------------------------------
__global__ __launch_bounds__(1024) void k_scan1024(
    const u32* __restrict__ stot, u32* __restrict__ sstart,
    u32* __restrict__ gcur, int E) {
    __shared__ u32 tmp[1024];
    const int t = threadIdx.x;
    u32 v = stot[t];
    tmp[t] = v;
    __syncthreads();
    for (int off = 1; off < 1024; off <<= 1) {
        u32 u = (t >= off) ? tmp[t - off] : 0;
        __syncthreads();
        tmp[t] += u;
        __syncthreads();
    }
    u32 ex = tmp[t] - v;
    sstart[t] = ex;
    gcur[t] = ex;
    if (t == 1023) sstart[1024] = (u32)E;
}

// ---------------------------------------------------------------------------
// K3: partition. Block counting-sorts a 12288-edge chunk in LDS, then copies
//     each slice's run to global pk[] as a DENSE consecutive-word run at a
//     position reserved with one atomicAdd per run. No scattered 4B stores.
// ---------------------------------------------------------------------------
__global__ __launch_bounds__(256) void k_part(
    const int* __restrict__ row, const int* __restrict__ col,
    u32* __restrict__ gcur, u32* __restrict__ pk,
    int E, u32 magic, int R) {
    __shared__ u32 startv[NS];   // 4 KB: exclusive starts (chunk-local)
    __shared__ u32 cur[NS];      // 4 KB: counts, then running cursors
    __shared__ u32 wsum[256];    // 1 KB: scan workspace
    __shared__ u32 pkbuf[CH];    // 48 KB: sorted packed edges
    const int lo = blockIdx.x * CH, hi = min(E, lo + CH);

    for (int t = threadIdx.x; t < NS; t += 256) cur[t] = 0;
    __syncthreads();
    for (int e = lo + threadIdx.x; e < hi; e += 256)
        atomicAdd(&cur[slice_of(__builtin_nontemporal_load(&row[e]), magic)], 1u);
    __syncthreads();
    // exclusive scan cur -> startv (thread t owns 4 slices)
    {
        const int t = threadIdx.x;
        u32 c0 = cur[4 * t], c1 = cur[4 * t + 1], c2 = cur[4 * t + 2], c3 = cur[4 * t + 3];
        u32 s4 = c0 + c1 + c2 + c3;
        wsum[t] = s4;
        __syncthreads();
        for (int off = 1; off < 256; off <<= 1) {
            u32 u = (t >= off) ? wsum[t - off] : 0;
            __syncthreads();
            wsum[t] += u;
            __syncthreads();
        }
        u32 run = wsum[t] - s4;
        startv[4 * t] = run; run += c0;
        startv[4 * t + 1] = run; run += c1;
        startv[4 * t + 2] = run; run += c2;
        startv[4 * t + 3] = run; run += c3;
    }
    __syncthreads();
    for (int t = threadIdx.x; t < NS; t += 256) cur[t] = startv[t];
    __syncthreads();
    // scatter chunk into LDS, sorted by slice
    for (int e = lo + threadIdx.x; e < hi; e += 256) {
        int rw = __builtin_nontemporal_load(&row[e]);
        int cw = __builtin_nontemporal_load(&col[e]);
        int s = slice_of(rw, magic);
        u32 pos = atomicAdd(&cur[s], 1u);
        pkbuf[pos] = ((u32)(rw - s * R) << CSHIFT) | (u32)cw;
    }
    __syncthreads();
    // dense run copy-out, one reservation per (block,slice)
    const int wave = threadIdx.x >> 6, lane = threadIdx.x & 63;
    const u32 total = (u32)(hi - lo);
    for (int s = wave; s < NS; s += 4) {
        u32 b0 = startv[s];
        u32 b1 = (s + 1 < NS) ? startv[s + 1] : total;
        int len = (int)(b1 - b0);
        if (len == 0) continue;
        u32 g;
        if (lane == 0) g = atomicAdd(&gcur[s], (u32)len);
        g = __shfl(g, 0);
        for (int l = lane; l < len; l += 64)
            pk[g + l] = pkbuf[b0 + l];
    }
}

// ---------------------------------------------------------------------------
// K4: per-slice degrees -> dinv (sequential writes).
// ---------------------------------------------------------------------------
__global__ __launch_bounds__(256) void k_deg(
    const u32* __restrict__ pk, const u32* __restrict__ sstart,
    float* __restrict__ dinv, int n, int R) {
    __shared__ u32 cnt[128];
    const int s = blockIdx.x, lo = s * R;
    if (threadIdx.x < 128) cnt[threadIdx.x] = 0;
    __syncthreads();
    const u32 beg = sstart[s], end = sstart[s + 1];
    for (u32 i = beg + threadIdx.x; i < end; i += 256)
        atomicAdd(&cnt[__builtin_nontemporal_load(&pk[i]) >> CSHIFT], 1u);
    __syncthreads();
    for (int t = threadIdx.x; t < R && lo + t < n; t += 256)
        dinv[lo + t] = rsqrtf((float)(cnt[t] + 1u));
}

// ---------------------------------------------------------------------------
// K5: GEMM h[i][:] = bf16( dinv[i] * (x[i] @ W) ), 4 rows/wave (proven).
// ---------------------------------------------------------------------------
__global__ __launch_bounds__(256) void k_gemm(
    const float* __restrict__ x, const float* __restrict__ W,
    const float* __restrict__ dinv, unsigned short* __restrict__ h, int n) {
    __shared__ float Ws[D_IN * D_OUT];
    __shared__ float xs[4][4][D_IN];
    for (int idx = threadIdx.x; idx < D_IN * D_OUT; idx += 256)
        Ws[idx] = W[idx];
    __syncthreads();

    const int wave = threadIdx.x >> 6;
    const int lane = threadIdx.x & 63;
    float* xw = &xs[wave][0][0];

    for (int i0 = (blockIdx.x * 4 + wave) * 4; i0 < n; i0 += gridDim.x * 16) {
#pragma unroll
        for (int r = 0; r < 4; ++r) {
            int i = min(i0 + r, n - 1);
            *(float2*)&xw[r * D_IN + lane * 2] =
                *(const float2*)&x[(size_t)i * D_IN + lane * 2];
        }
        float a0 = 0.f, a1 = 0.f, a2 = 0.f, a3 = 0.f;
#pragma unroll
        for (int k4 = 0; k4 < D_IN; k4 += 4) {
            float4 x0 = *(float4*)&xw[0 * D_IN + k4];
            float4 x1 = *(float4*)&xw[1 * D_IN + k4];
            float4 x2 = *(float4*)&xw[2 * D_IN + k4];
            float4 x3 = *(float4*)&xw[3 * D_IN + k4];
#pragma unroll
            for (int u = 0; u < 4; ++u) {
                float wv = Ws[(k4 + u) * D_OUT + lane];
                a0 = fmaf((&x0.x)[u], wv, a0);
                a1 = fmaf((&x1.x)[u], wv, a1);
                a2 = fmaf((&x2.x)[u], wv, a2);
                a3 = fmaf((&x3.x)[u], wv, a3);
            }
        }
        int nr = min(4, n - i0);
        if (nr == 4) {
            h[(size_t)(i0 + 0) * D_OUT + lane] = f2bf(dinv[i0 + 0] * a0);
            h[(size_t)(i0 + 1) * D_OUT + lane] = f2bf(dinv[i0 + 1] * a1);
            h[(size_t)(i0 + 2) * D_OUT + lane] = f2bf(dinv[i0 + 2] * a2);
            h[(size_t)(i0 + 3) * D_OUT + lane] = f2bf(dinv[i0 + 3] * a3);
        } else {
            for (int r = 0; r < nr; ++r) {
                float a = (r == 0) ? a0 : (r == 1) ? a1 : (r == 2) ? a2 : a3;
                h[(size_t)(i0 + r) * D_OUT + lane] = f2bf(dinv[i0 + r] * a);
            }
        }
    }
}

// ---------------------------------------------------------------------------
// K6: aggregation, one WG (8 waves) per slice. Stage+counting-sort the
//     slice's edges in LDS grouped by local row, then PULL: each wave owns
//     13 rows; per edge a half-wave (32 lanes x 4B) gathers the full 128B
//     h row; fp32 register accumulators; fused epilogue. No atomics in the
//     gather loop.
// ---------------------------------------------------------------------------
__global__ __launch_bounds__(512) void k_aggr(
    const unsigned short* __restrict__ h, const u32* __restrict__ pk,
    const u32* __restrict__ sstart, const float* __restrict__ dinv,
    const float* __restrict__ bias, float* __restrict__ out, int n, int R) {
    __shared__ u32 cnt[128], eptr[128], cur[128];
    __shared__ u32 pkl[ACH];    // staged packed edges (16 KB)
    __shared__ u32 cols[ACH];   // row-sorted cols (16 KB)
    const int s = blockIdx.x, lo = s * R;
    const int rows = min(R, n - lo);
    const int wave = threadIdx.x >> 6, lane = threadIdx.x & 63;
    const int half = lane >> 5, l31 = lane & 31;
    const u32* hp = (const u32*)h;

    float ax[13], ay[13];
#pragma unroll
    for (int k = 0; k < 13; ++k) { ax[k] = 0.f; ay[k] = 0.f; }

    const u32 beg = sstart[s], end = sstart[s + 1];
    for (u32 cb = beg; cb < end; cb += ACH) {
        const u32 ce = min(end, cb + (u32)ACH);
        if (threadIdx.x < 128) cnt[threadIdx.x] = 0;
        __syncthreads();
        for (u32 i = cb + threadIdx.x; i < ce; i += 512) {
            u32 w = __builtin_nontemporal_load(&pk[i]);
            pkl[i - cb] = w;
            atomicAdd(&cnt[w >> CSHIFT], 1u);
        }
        __syncthreads();
        // exclusive scan of cnt[128]
        if (threadIdx.x < 128) eptr[threadIdx.x] = cnt[threadIdx.x];
        __syncthreads();
        for (int off = 1; off < 128; off <<= 1) {
            u32 u = 0;
            if (threadIdx.x < 128 && threadIdx.x >= off) u = eptr[threadIdx.x - off];
            __syncthreads();
            if (threadIdx.x < 128) eptr[threadIdx.x] += u;
            __syncthreads();
        }
        if (threadIdx.x < 128) {
            u32 ex = eptr[threadIdx.x] - cnt[threadIdx.x];
            eptr[threadIdx.x] = ex;
            cur[threadIdx.x] = ex;
        }
        __syncthreads();
        // sort cols by local row
        const u32 m = ce - cb;
        for (u32 i = threadIdx.x; i < m; i += 512) {
            u32 w = pkl[i];
            u32 pos = atomicAdd(&cur[w >> CSHIFT], 1u);
            cols[pos] = w & CMASK;
        }
        __syncthreads();
        // pull: wave owns rows q = wave + 8k
#pragma unroll
        for (int k = 0; k < 13; ++k) {
            int q = wave + 8 * k;
            if (q < rows) {
                int b0 = (int)eptr[q], b1 = b0 + (int)cnt[q];
                for (int t = b0 + half; t < b1; t += 2) {
                    u32 c = cols[t];
                    u32 u = hp[(size_t)c * 32 + l31];
                    ax[k] += u2f(u << 16);
                    ay[k] += u2f(u & 0xffff0000u);
                }
            }
        }
        __syncthreads();
    }
    // combine halves + self term + finalize
#pragma unroll
    for (int k = 0; k < 13; ++k) {
        int q = wave + 8 * k;
        if (q >= rows) continue;
        float a_ = ax[k] + __shfl_xor(ax[k], 32);
        float b_ = ay[k] + __shfl_xor(ay[k], 32);
        int i = lo + q;
        u32 us = hp[(size_t)i * 32 + l31];
        a_ += u2f(us << 16);
        b_ += u2f(us & 0xffff0000u);
        float d = dinv[i];
        float2 bb = *(const float2*)&bias[l31 * 2];
        float2 r;
        r.x = fmaxf(fmaf(d, a_, bb.x), 0.f);
        r.y = fmaxf(fmaf(d, b_, bb.y), 0.f);
        if (half == 0)
            *(float2*)&out[(size_t)i * D_OUT + l31 * 2] = r;
    }
}

extern "C" void kernel_launch(void* const* d_in, const int* in_sizes, int n_in,
                              void* d_out, int out_size, void* d_ws, size_t ws_size,
                              hipStream_t stream) {
    const float* x  = (const float*)d_in[0];
    const int*   ei = (const int*)d_in[1];   // [2][E] int32: row=targets, col=sources
    const float* W  = (const float*)d_in[2];
    const float* b  = (const float*)d_in[3];
    const int n = in_sizes[0] / D_IN;   // 100000
    const int E = in_sizes[1] / 2;      // 3200000
    const int* row = ei;
    const int* col = ei + E;

    // workspace: h 12.8MB | pk 12.8MB | dinv 0.4MB | stot/sstart/gcur ~12KB
    char* basep = (char*)d_ws;
    size_t off = 0;
    auto alloc = [&](size_t bytes) { char* p = basep + off; off += (bytes + 63) & ~(size_t)63; return p; };
    unsigned short* h      = (unsigned short*)alloc((size_t)n * D_OUT * 2);
    u32*            pk     = (u32*)alloc((size_t)E * 4);
    float*          dinv   = (float*)alloc((size_t)n * 4);
    u32*            stot   = (u32*)alloc((size_t)NS * 4);
    u32*            sstart = (u32*)alloc((size_t)(NS + 1) * 4);
    u32*            gcur   = (u32*)alloc((size_t)NS * 4);

    const int R = (n + NS - 1) / NS;            // 98
    const int NSW = (n + R - 1) / R;            // 1021 active slices
    const int NPB = (E + CH - 1) / CH;          // 261 partition blocks
    const u32 magic = (u32)(((1ULL << 35) + R - 1) / R);

    hipMemsetAsync(stot, 0, (size_t)NS * 4, stream);
    k_hist<<<512, 256, 0, stream>>>(row, stot, E, magic);
    k_scan1024<<<1, 1024, 0, stream>>>(stot, sstart, gcur, E);
    k_part<<<NPB, 256, 0, stream>>>(row, col, gcur, pk, E, magic, R);
    k_deg<<<NSW, 256, 0, stream>>>(pk, sstart, dinv, n, R);
    k_gemm<<<2048, 256, 0, stream>>>(x, W, dinv, h, n);
    k_aggr<<<NSW, 512, 0, stream>>>(h, pk, sstart, dinv, b, (float*)d_out, n, R);
}

// Round 7
// 348.345 us; speedup vs baseline: 3.7621x; 1.7546x over previous
//
#include <hip/hip_runtime.h>

#define D_IN 128
#define D_OUT 64
#define RSH 7           // rows per slice = 128 (power of 2): slice = row >> 7
#define RPS 128
#define NS 1024         // slice array bound (782 used for n=100k)
#define ACH 4096        // edges per k_aggr staging chunk
#define CSHIFT 17
#define CMASK 0x1FFFFu  // 17-bit col (n < 131072); rowLocal (7b) in bits 17..23

typedef unsigned int u32;

// --- bf16 helpers ----------------------------------------------------------
__device__ inline float u2f(u32 u) {
    union { u32 i; float f; } v; v.i = u; return v.f;
}
__device__ inline float bf2f(unsigned short u) { return u2f(((u32)u) << 16); }
__device__ inline unsigned short f2bf(float f) {
    union { float f; u32 i; } v; v.f = f;
    u32 r = v.i + 0x7fffu + ((v.i >> 16) & 1u);
    return (unsigned short)(r >> 16);
}

// ---------------------------------------------------------------------------
// K1: global per-slice totals (LDS hist + tiny global atomics).
// ---------------------------------------------------------------------------
__global__ __launch_bounds__(256) void k_hist(
    const int* __restrict__ row, u32* __restrict__ stot, int E) {
    __shared__ u32 cnt[NS];
    for (int t = threadIdx.x; t < NS; t += 256) cnt[t] = 0;
    __syncthreads();
    const int stride = gridDim.x * 256;
    for (int e = blockIdx.x * 256 + threadIdx.x; e < E; e += stride)
        atomicAdd(&cnt[(u32)__builtin_nontemporal_load(&row[e]) >> RSH], 1u);
    __syncthreads();
    for (int t = threadIdx.x; t < NS; t += 256) {
        u32 c = cnt[t];
        if (c) atomicAdd(&stot[t], c);
    }
}

// ---------------------------------------------------------------------------
// K2: exclusive scan of stot[1024] -> sstart[1025]; init gcur = sstart.
// ---------------------------------------------------------------------------
__global__ __launch_bounds__(1024) void k_scan1024(
    const u32* __restrict__ stot, u32* __restrict__ sstart,
    u32* __restrict__ gcur, int E) {
    __shared__ u32 tmp[1024];
    const int t = threadIdx.x;
    u32 v = stot[t];
    tmp[t] = v;
    __syncthreads();
    for (int off = 1; off < 1024; off <<= 1) {
        u32 u = (t >= off) ? tmp[t - off] : 0;
        __syncthreads();
        tmp[t] += u;
        __syncthreads();
    }
    u32 ex = tmp[t] - v;
    sstart[t] = ex;
    gcur[t] = ex;
    if (t == 1023) sstart[1024] = (u32)E;
}

// ---------------------------------------------------------------------------
// K3: partition, direct-scatter with dense per-(block,slice) runs.
//     Pass A: LDS slice histogram of this block's chunk (4 KB LDS only).
//     Reserve: one global atomicAdd per non-empty (block,slice).
//     Pass B: stream edges again, store packed word straight to global pk[]
//     at LDS-cursor positions. Runs (~16 words) assemble in L2 (line is
//     written only by this block, within this block's short pass).
// ---------------------------------------------------------------------------
__global__ __launch_bounds__(512) void k_part(
    const int* __restrict__ row, const int* __restrict__ col,
    u32* __restrict__ gcur, u32* __restrict__ pk, int E, int CH) {
    __shared__ u32 cnt[NS];
    const int lo = blockIdx.x * CH, hi = min(E, lo + CH);
    for (int t = threadIdx.x; t < NS; t += 512) cnt[t] = 0;
    __syncthreads();
    for (int e = lo + threadIdx.x; e < hi; e += 512)
        atomicAdd(&cnt[(u32)__builtin_nontemporal_load(&row[e]) >> RSH], 1u);
    __syncthreads();
    for (int t = threadIdx.x; t < NS; t += 512) {
        u32 c = cnt[t];
        cnt[t] = c ? atomicAdd(&gcur[t], c) : 0u;
    }
    __syncthreads();
    for (int e = lo + threadIdx.x; e < hi; e += 512) {
        u32 rw = (u32)__builtin_nontemporal_load(&row[e]);
        u32 cw = (u32)__builtin_nontemporal_load(&col[e]);
        u32 pos = atomicAdd(&cnt[rw >> RSH], 1u);
        pk[pos] = ((rw & (RPS - 1u)) << CSHIFT) | cw;   // normal store: L2-combine
    }
}

// ---------------------------------------------------------------------------
// K4: per-slice degrees -> dinv (sequential writes).
// ---------------------------------------------------------------------------
__global__ __launch_bounds__(256) void k_deg(
    const u32* __restrict__ pk, const u32* __restrict__ sstart,
    float* __restrict__ dinv, int n) {
    __shared__ u32 cnt[RPS];
    const int s = blockIdx.x, lo = s << RSH;
    if (threadIdx.x < RPS) cnt[threadIdx.x] = 0;
    __syncthreads();
    const u32 beg = sstart[s], end = sstart[s + 1];
    for (u32 i = beg + threadIdx.x; i < end; i += 256)
        atomicAdd(&cnt[__builtin_nontemporal_load(&pk[i]) >> CSHIFT], 1u);
    __syncthreads();
    for (int t = threadIdx.x; t < RPS && lo + t < n; t += 256)
        dinv[lo + t] = rsqrtf((float)(cnt[t] + 1u));
}

// ---------------------------------------------------------------------------
// K5: GEMM h[i][:] = bf16( dinv[i] * (x[i] @ W) ), 4 rows/wave (proven).
// ---------------------------------------------------------------------------
__global__ __launch_bounds__(256) void k_gemm(
    const float* __restrict__ x, const float* __restrict__ W,
    const float* __restrict__ dinv, unsigned short* __restrict__ h, int n) {
    __shared__ float Ws[D_IN * D_OUT];
    __shared__ float xs[4][4][D_IN];
    for (int idx = threadIdx.x; idx < D_IN * D_OUT; idx += 256)
        Ws[idx] = W[idx];
    __syncthreads();

    const int wave = threadIdx.x >> 6;
    const int lane = threadIdx.x & 63;
    float* xw = &xs[wave][0][0];

    for (int i0 = (blockIdx.x * 4 + wave) * 4; i0 < n; i0 += gridDim.x * 16) {
#pragma unroll
        for (int r = 0; r < 4; ++r) {
            int i = min(i0 + r, n - 1);
            *(float2*)&xw[r * D_IN + lane * 2] =
                *(const float2*)&x[(size_t)i * D_IN + lane * 2];
        }
        float a0 = 0.f, a1 = 0.f, a2 = 0.f, a3 = 0.f;
#pragma unroll
        for (int k4 = 0; k4 < D_IN; k4 += 4) {
            float4 x0 = *(float4*)&xw[0 * D_IN + k4];
            float4 x1 = *(float4*)&xw[1 * D_IN + k4];
            float4 x2 = *(float4*)&xw[2 * D_IN + k4];
            float4 x3 = *(float4*)&xw[3 * D_IN + k4];
#pragma unroll
            for (int u = 0; u < 4; ++u) {
                float wv = Ws[(k4 + u) * D_OUT + lane];
                a0 = fmaf((&x0.x)[u], wv, a0);
                a1 = fmaf((&x1.x)[u], wv, a1);
                a2 = fmaf((&x2.x)[u], wv, a2);
                a3 = fmaf((&x3.x)[u], wv, a3);
            }
        }
        int nr = min(4, n - i0);
        if (nr == 4) {
            h[(size_t)(i0 + 0) * D_OUT + lane] = f2bf(dinv[i0 + 0] * a0);
            h[(size_t)(i0 + 1) * D_OUT + lane] = f2bf(dinv[i0 + 1] * a1);
            h[(size_t)(i0 + 2) * D_OUT + lane] = f2bf(dinv[i0 + 2] * a2);
            h[(size_t)(i0 + 3) * D_OUT + lane] = f2bf(dinv[i0 + 3] * a3);
        } else {
            for (int r = 0; r < nr; ++r) {
                float a = (r == 0) ? a0 : (r == 1) ? a1 : (r == 2) ? a2 : a3;
                h[(size_t)(i0 + r) * D_OUT + lane] = f2bf(dinv[i0 + r] * a);
            }
        }
    }
}

// ---------------------------------------------------------------------------
// K6: aggregation, one WG (8 waves) per 128-row slice. Stage + counting-sort
//     the slice's edges in LDS grouped by local row, then PULL: each wave
//     owns 16 rows; per edge a half-wave (32 lanes x 4B) gathers the full
//     128B h row; fp32 register accumulators; fused epilogue. No atomics in
//     the gather loop.
// ---------------------------------------------------------------------------
__global__ __launch_bounds__(512) void k_aggr(
    const unsigned short* __restrict__ h, const u32* __restrict__ pk,
    const u32* __restrict__ sstart, const float* __restrict__ dinv,
    const float* __restrict__ bias, float* __restrict__ out, int n) {
    __shared__ u32 cnt[RPS], eptr[RPS], cur[RPS];
    __shared__ u32 pkl[ACH];    // staged packed edges (16 KB)
    __shared__ u32 cols[ACH];   // row-sorted cols (16 KB)
    const int s = blockIdx.x, lo = s << RSH;
    const int rows = min(RPS, n - lo);
    const int wave = threadIdx.x >> 6, lane = threadIdx.x & 63;
    const int half = lane >> 5, l31 = lane & 31;
    const u32* hp = (const u32*)h;

    float ax[16], ay[16];
#pragma unroll
    for (int k = 0; k < 16; ++k) { ax[k] = 0.f; ay[k] = 0.f; }

    const u32 beg = sstart[s], end = sstart[s + 1];
    for (u32 cb = beg; cb < end; cb += ACH) {
        const u32 ce = min(end, cb + (u32)ACH);
        if (threadIdx.x < RPS) cnt[threadIdx.x] = 0;
        __syncthreads();
        for (u32 i = cb + threadIdx.x; i < ce; i += 512) {
            u32 w = __builtin_nontemporal_load(&pk[i]);
            pkl[i - cb] = w;
            atomicAdd(&cnt[w >> CSHIFT], 1u);
        }
        __syncthreads();
        if (threadIdx.x < RPS) eptr[threadIdx.x] = cnt[threadIdx.x];
        __syncthreads();
        for (int off = 1; off < RPS; off <<= 1) {
            u32 u = 0;
            if (threadIdx.x < RPS && threadIdx.x >= off) u = eptr[threadIdx.x - off];
            __syncthreads();
            if (threadIdx.x < RPS) eptr[threadIdx.x] += u;
            __syncthreads();
        }
        if (threadIdx.x < RPS) {
            u32 ex = eptr[threadIdx.x] - cnt[threadIdx.x];
            eptr[threadIdx.x] = ex;
            cur[threadIdx.x] = ex;
        }
        __syncthreads();
        const u32 m = ce - cb;
        for (u32 i = threadIdx.x; i < m; i += 512) {
            u32 w = pkl[i];
            u32 pos = atomicAdd(&cur[w >> CSHIFT], 1u);
            cols[pos] = w & CMASK;
        }
        __syncthreads();
#pragma unroll
        for (int k = 0; k < 16; ++k) {
            int q = wave + 8 * k;
            if (q < rows) {
                int b0 = (int)eptr[q], b1 = b0 + (int)cnt[q];
                for (int t = b0 + half; t < b1; t += 2) {
                    u32 c = cols[t];
                    u32 u = hp[(size_t)c * 32 + l31];
                    ax[k] += u2f(u << 16);
                    ay[k] += u2f(u & 0xffff0000u);
                }
            }
        }
        __syncthreads();
    }
    // combine halves + self term + finalize
#pragma unroll
    for (int k = 0; k < 16; ++k) {
        int q = wave + 8 * k;
        if (q >= rows) continue;
        float a_ = ax[k] + __shfl_xor(ax[k], 32);
        float b_ = ay[k] + __shfl_xor(ay[k], 32);
        int i = lo + q;
        u32 us = hp[(size_t)i * 32 + l31];
        a_ += u2f(us << 16);
        b_ += u2f(us & 0xffff0000u);
        float d = dinv[i];
        float2 bb = *(const float2*)&bias[l31 * 2];
        float2 r;
        r.x = fmaxf(fmaf(d, a_, bb.x), 0.f);
        r.y = fmaxf(fmaf(d, b_, bb.y), 0.f);
        if (half == 0)
            *(float2*)&out[(size_t)i * D_OUT + l31 * 2] = r;
    }
}

extern "C" void kernel_launch(void* const* d_in, const int* in_sizes, int n_in,
                              void* d_out, int out_size, void* d_ws, size_t ws_size,
                              hipStream_t stream) {
    const float* x  = (const float*)d_in[0];
    const int*   ei = (const int*)d_in[1];   // [2][E] int32: row=targets, col=sources
    const float* W  = (const float*)d_in[2];
    const float* b  = (const float*)d_in[3];
    const int n = in_sizes[0] / D_IN;   // 100000
    const int E = in_sizes[1] / 2;      // 3200000
    const int* row = ei;
    const int* col = ei + E;

    // workspace: h 12.8MB | pk 12.8MB | dinv 0.4MB | stot/sstart/gcur ~12KB
    char* basep = (char*)d_ws;
    size_t off = 0;
    auto alloc = [&](size_t bytes) { char* p = basep + off; off += (bytes + 63) & ~(size_t)63; return p; };
    unsigned short* h      = (unsigned short*)alloc((size_t)n * D_OUT * 2);
    u32*            pk     = (u32*)alloc((size_t)E * 4);
    float*          dinv   = (float*)alloc((size_t)n * 4);
    u32*            stot   = (u32*)alloc((size_t)NS * 4);
    u32*            sstart = (u32*)alloc((size_t)(NS + 1) * 4);
    u32*            gcur   = (u32*)alloc((size_t)NS * 4);

    const int NSW = (n + RPS - 1) / RPS;        // 782 active slices
    const int NPB = 256;                        // partition blocks
    const int CH  = (E + NPB - 1) / NPB;        // 12500 edges per block

    hipMemsetAsync(stot, 0, (size_t)NS * 4, stream);
    k_hist<<<512, 256, 0, stream>>>(row, stot, E);
    k_scan1024<<<1, 1024, 0, stream>>>(stot, sstart, gcur, E);
    k_part<<<NPB, 512, 0, stream>>>(row, col, gcur, pk, E, CH);
    k_deg<<<NSW, 256, 0, stream>>>(pk, sstart, dinv, n);
    k_gemm<<<2048, 256, 0, stream>>>(x, W, dinv, h, n);
    k_aggr<<<NSW, 512, 0, stream>>>(h, pk, sstart, dinv, b, (float*)d_out, n);
}

// Round 8
// 231.600 us; speedup vs baseline: 5.6585x; 1.5041x over previous
//
#include <hip/hip_runtime.h>

#define D_IN 128
#define D_OUT 64
#define RSH 7           // rows per slice = 128 (power of 2): slice = row >> 7
#define RPS 128
#define NS 1024         // slice array bound (782 used for n=100k)
#define ACH 5120        // edges per k_aggr chunk (> max slice size ~4300)
#define CSHIFT 17
#define CMASK 0x1FFFFu  // 17-bit col (n < 131072); rowLocal (7b) in bits 17..23

typedef unsigned int u32;

// --- bf16 helpers ----------------------------------------------------------
__device__ inline float u2f(u32 u) {
    union { u32 i; float f; } v; v.i = u; return v.f;
}
__device__ inline float bf2f(unsigned short u) { return u2f(((u32)u) << 16); }
__device__ inline unsigned short f2bf(float f) {
    union { float f; u32 i; } v; v.f = f;
    u32 r = v.i + 0x7fffu + ((v.i >> 16) & 1u);
    return (unsigned short)(r >> 16);
}

// ---------------------------------------------------------------------------
// K1: global per-slice totals (LDS hist + tiny global atomics).
// ---------------------------------------------------------------------------
__global__ __launch_bounds__(256) void k_hist(
    const int* __restrict__ row, u32* __restrict__ stot, int E) {
    __shared__ u32 cnt[NS];
    for (int t = threadIdx.x; t < NS; t += 256) cnt[t] = 0;
    __syncthreads();
    const int stride = gridDim.x * 256;
    for (int e = blockIdx.x * 256 + threadIdx.x; e < E; e += stride)
        atomicAdd(&cnt[(u32)__builtin_nontemporal_load(&row[e]) >> RSH], 1u);
    __syncthreads();
    for (int t = threadIdx.x; t < NS; t += 256) {
        u32 c = cnt[t];
        if (c) atomicAdd(&stot[t], c);
    }
}

// ---------------------------------------------------------------------------
// K2: exclusive scan of stot[1024] -> sstart[1025]; init gcur = sstart.
// ---------------------------------------------------------------------------
__global__ __launch_bounds__(1024) void k_scan1024(
    const u32* __restrict__ stot, u32* __restrict__ sstart,
    u32* __restrict__ gcur, int E) {
    __shared__ u32 tmp[1024];
    const int t = threadIdx.x;
    u32 v = stot[t];
    tmp[t] = v;
    __syncthreads();
    for (int off = 1; off < 1024; off <<= 1) {
        u32 u = (t >= off) ? tmp[t - off] : 0;
        __syncthreads();
        tmp[t] += u;
        __syncthreads();
    }
    u32 ex = tmp[t] - v;
    sstart[t] = ex;
    gcur[t] = ex;
    if (t == 1023) sstart[1024] = (u32)E;
}

// ---------------------------------------------------------------------------
// K3: partition, direct-scatter with dense per-(block,slice) runs (proven
//     round 7: dense ~16-word runs assemble in L2, ~2x write amplification).
// ---------------------------------------------------------------------------
__global__ __launch_bounds__(512) void k_part(
    const int* __restrict__ row, const int* __restrict__ col,
    u32* __restrict__ gcur, u32* __restrict__ pk, int E, int CH) {
    __shared__ u32 cnt[NS];
    const int lo = blockIdx.x * CH, hi = min(E, lo + CH);
    for (int t = threadIdx.x; t < NS; t += 512) cnt[t] = 0;
    __syncthreads();
    for (int e = lo + threadIdx.x; e < hi; e += 512)
        atomicAdd(&cnt[(u32)__builtin_nontemporal_load(&row[e]) >> RSH], 1u);
    __syncthreads();
    for (int t = threadIdx.x; t < NS; t += 512) {
        u32 c = cnt[t];
        cnt[t] = c ? atomicAdd(&gcur[t], c) : 0u;
    }
    __syncthreads();
    for (int e = lo + threadIdx.x; e < hi; e += 512) {
        u32 rw = (u32)__builtin_nontemporal_load(&row[e]);
        u32 cw = (u32)__builtin_nontemporal_load(&col[e]);
        u32 pos = atomicAdd(&cnt[rw >> RSH], 1u);
        pk[pos] = ((rw & (RPS - 1u)) << CSHIFT) | cw;   // normal store: L2-combine
    }
}

// ---------------------------------------------------------------------------
// K4: per-slice degrees -> dinv (sequential writes).
// ---------------------------------------------------------------------------
__global__ __launch_bounds__(256) void k_deg(
    const u32* __restrict__ pk, const u32* __restrict__ sstart,
    float* __restrict__ dinv, int n) {
    __shared__ u32 cnt[RPS];
    const int s = blockIdx.x, lo = s << RSH;
    if (threadIdx.x < RPS) cnt[threadIdx.x] = 0;
    __syncthreads();
    const u32 beg = sstart[s], end = sstart[s + 1];
    for (u32 i = beg + threadIdx.x; i < end; i += 256)
        atomicAdd(&cnt[pk[i] >> CSHIFT], 1u);
    __syncthreads();
    for (int t = threadIdx.x; t < RPS && lo + t < n; t += 256)
        dinv[lo + t] = rsqrtf((float)(cnt[t] + 1u));
}

// ---------------------------------------------------------------------------
// K5: GEMM h[i][:] = bf16( dinv[i] * (x[i] @ W) ), 4 rows/wave (proven).
// ---------------------------------------------------------------------------
__global__ __launch_bounds__(256) void k_gemm(
    const float* __restrict__ x, const float* __restrict__ W,
    const float* __restrict__ dinv, unsigned short* __restrict__ h, int n) {
    __shared__ float Ws[D_IN * D_OUT];
    __shared__ float xs[4][4][D_IN];
    for (int idx = threadIdx.x; idx < D_IN * D_OUT; idx += 256)
        Ws[idx] = W[idx];
    __syncthreads();

    const int wave = threadIdx.x >> 6;
    const int lane = threadIdx.x & 63;
    float* xw = &xs[wave][0][0];

    for (int i0 = (blockIdx.x * 4 + wave) * 4; i0 < n; i0 += gridDim.x * 16) {
#pragma unroll
        for (int r = 0; r < 4; ++r) {
            int i = min(i0 + r, n - 1);
            *(float2*)&xw[r * D_IN + lane * 2] =
                *(const float2*)&x[(size_t)i * D_IN + lane * 2];
        }
        float a0 = 0.f, a1 = 0.f, a2 = 0.f, a3 = 0.f;
#pragma unroll
        for (int k4 = 0; k4 < D_IN; k4 += 4) {
            float4 x0 = *(float4*)&xw[0 * D_IN + k4];
            float4 x1 = *(float4*)&xw[1 * D_IN + k4];
            float4 x2 = *(float4*)&xw[2 * D_IN + k4];
            float4 x3 = *(float4*)&xw[3 * D_IN + k4];
#pragma unroll
            for (int u = 0; u < 4; ++u) {
                float wv = Ws[(k4 + u) * D_OUT + lane];
                a0 = fmaf((&x0.x)[u], wv, a0);
                a1 = fmaf((&x1.x)[u], wv, a1);
                a2 = fmaf((&x2.x)[u], wv, a2);
                a3 = fmaf((&x3.x)[u], wv, a3);
            }
        }
        int nr = min(4, n - i0);
        if (nr == 4) {
            h[(size_t)(i0 + 0) * D_OUT + lane] = f2bf(dinv[i0 + 0] * a0);
            h[(size_t)(i0 + 1) * D_OUT + lane] = f2bf(dinv[i0 + 1] * a1);
            h[(size_t)(i0 + 2) * D_OUT + lane] = f2bf(dinv[i0 + 2] * a2);
            h[(size_t)(i0 + 3) * D_OUT + lane] = f2bf(dinv[i0 + 3] * a3);
        } else {
            for (int r = 0; r < nr; ++r) {
                float a = (r == 0) ? a0 : (r == 1) ? a1 : (r == 2) ? a2 : a3;
                h[(size_t)(i0 + r) * D_OUT + lane] = f2bf(dinv[i0 + r] * a);
            }
        }
    }
}

// ---------------------------------------------------------------------------
// K6: aggregation, one WG (8 waves) per 128-row slice. Counting-sort the
//     slice's edges by local row in LDS (cols[] only; pk read twice from the
//     L2-hot stream), then PULL with deep ILP: each wave owns 16 rows; per
//     row the two half-waves each keep up to 8 independent 128B h-row
//     gathers in flight (8/4/1 unroll cascade). fp32 register accumulators;
//     fused dinv/bias/relu epilogue. No atomics in the gather loop.
// ---------------------------------------------------------------------------
__global__ __launch_bounds__(512) void k_aggr(
    const unsigned short* __restrict__ h, const u32* __restrict__ pk,
    const u32* __restrict__ sstart, const float* __restrict__ dinv,
    const float* __restrict__ bias, float* __restrict__ out, int n) {
    __shared__ u32 cnt[RPS], eptr[RPS], cur[RPS];
    __shared__ u32 cols[ACH];   // row-sorted cols (20 KB)
    const int s = blockIdx.x, lo = s << RSH;
    const int rows = min(RPS, n - lo);
    const int wave = threadIdx.x >> 6, lane = threadIdx.x & 63;
    const int half = lane >> 5, l31 = lane & 31;
    const u32* hp = (const u32*)h;

    float ax[16], ay[16];
#pragma unroll
    for (int k = 0; k < 16; ++k) { ax[k] = 0.f; ay[k] = 0.f; }

    const u32 beg = sstart[s], end = sstart[s + 1];
    for (u32 cb = beg; cb < end; cb += ACH) {
        const u32 ce = min(end, cb + (u32)ACH);
        if (threadIdx.x < RPS) cnt[threadIdx.x] = 0;
        __syncthreads();
        for (u32 i = cb + threadIdx.x; i < ce; i += 512)
            atomicAdd(&cnt[pk[i] >> CSHIFT], 1u);
        __syncthreads();
        if (threadIdx.x < RPS) eptr[threadIdx.x] = cnt[threadIdx.x];
        __syncthreads();
        for (int off = 1; off < RPS; off <<= 1) {
            u32 u = 0;
            if (threadIdx.x < RPS && threadIdx.x >= off) u = eptr[threadIdx.x - off];
            __syncthreads();
            if (threadIdx.x < RPS) eptr[threadIdx.x] += u;
            __syncthreads();
        }
        if (threadIdx.x < RPS) {
            u32 ex = eptr[threadIdx.x] - cnt[threadIdx.x];
            eptr[threadIdx.x] = ex;
            cur[threadIdx.x] = ex;
        }
        __syncthreads();
        for (u32 i = cb + threadIdx.x; i < ce; i += 512) {
            u32 w = pk[i];
            u32 pos = atomicAdd(&cur[w >> CSHIFT], 1u);
            cols[pos] = w & CMASK;
        }
        __syncthreads();
        // pull with deep ILP: rows q = wave + 8k
#pragma unroll
        for (int k = 0; k < 16; ++k) {
            int q = wave + 8 * k;
            if (q < rows) {
                const int b1 = (int)eptr[q] + (int)cnt[q];
                int t = (int)eptr[q] + half;
                // 8 gathers in flight
                for (; t + 14 < b1; t += 16) {
                    u32 c0 = cols[t],      c1 = cols[t + 2];
                    u32 c2 = cols[t + 4],  c3 = cols[t + 6];
                    u32 c4 = cols[t + 8],  c5 = cols[t + 10];
                    u32 c6 = cols[t + 12], c7 = cols[t + 14];
                    u32 u0 = hp[(size_t)c0 * 32 + l31];
                    u32 u1 = hp[(size_t)c1 * 32 + l31];
                    u32 u2 = hp[(size_t)c2 * 32 + l31];
                    u32 u3 = hp[(size_t)c3 * 32 + l31];
                    u32 u4 = hp[(size_t)c4 * 32 + l31];
                    u32 u5 = hp[(size_t)c5 * 32 + l31];
                    u32 u6 = hp[(size_t)c6 * 32 + l31];
                    u32 u7 = hp[(size_t)c7 * 32 + l31];
                    ax[k] += u2f(u0 << 16); ay[k] += u2f(u0 & 0xffff0000u);
                    ax[k] += u2f(u1 << 16); ay[k] += u2f(u1 & 0xffff0000u);
                    ax[k] += u2f(u2 << 16); ay[k] += u2f(u2 & 0xffff0000u);
                    ax[k] += u2f(u3 << 16); ay[k] += u2f(u3 & 0xffff0000u);
                    ax[k] += u2f(u4 << 16); ay[k] += u2f(u4 & 0xffff0000u);
                    ax[k] += u2f(u5 << 16); ay[k] += u2f(u5 & 0xffff0000u);
                    ax[k] += u2f(u6 << 16); ay[k] += u2f(u6 & 0xffff0000u);
                    ax[k] += u2f(u7 << 16); ay[k] += u2f(u7 & 0xffff0000u);
                }
                // 4 in flight
                for (; t + 6 < b1; t += 8) {
                    u32 c0 = cols[t],     c1 = cols[t + 2];
                    u32 c2 = cols[t + 4], c3 = cols[t + 6];
                    u32 u0 = hp[(size_t)c0 * 32 + l31];
                    u32 u1 = hp[(size_t)c1 * 32 + l31];
                    u32 u2 = hp[(size_t)c2 * 32 + l31];
                    u32 u3 = hp[(size_t)c3 * 32 + l31];
                    ax[k] += u2f(u0 << 16); ay[k] += u2f(u0 & 0xffff0000u);
                    ax[k] += u2f(u1 << 16); ay[k] += u2f(u1 & 0xffff0000u);
                    ax[k] += u2f(u2 << 16); ay[k] += u2f(u2 & 0xffff0000u);
                    ax[k] += u2f(u3 << 16); ay[k] += u2f(u3 & 0xffff0000u);
                }
                // tail
                for (; t < b1; t += 2) {
                    u32 c = cols[t];
                    u32 u = hp[(size_t)c * 32 + l31];
                    ax[k] += u2f(u << 16); ay[k] += u2f(u & 0xffff0000u);
                }
            }
        }
        __syncthreads();
    }
    // combine halves + self term + finalize
#pragma unroll
    for (int k = 0; k < 16; ++k) {
        int q = wave + 8 * k;
        if (q >= rows) continue;
        float a_ = ax[k] + __shfl_xor(ax[k], 32);
        float b_ = ay[k] + __shfl_xor(ay[k], 32);
        int i = lo + q;
        u32 us = hp[(size_t)i * 32 + l31];
        a_ += u2f(us << 16);
        b_ += u2f(us & 0xffff0000u);
        float d = dinv[i];
        float2 bb = *(const float2*)&bias[l31 * 2];
        float2 r;
        r.x = fmaxf(fmaf(d, a_, bb.x), 0.f);
        r.y = fmaxf(fmaf(d, b_, bb.y), 0.f);
        if (half == 0)
            *(float2*)&out[(size_t)i * D_OUT + l31 * 2] = r;
    }
}

extern "C" void kernel_launch(void* const* d_in, const int* in_sizes, int n_in,
                              void* d_out, int out_size, void* d_ws, size_t ws_size,
                              hipStream_t stream) {
    const float* x  = (const float*)d_in[0];
    const int*   ei = (const int*)d_in[1];   // [2][E] int32: row=targets, col=sources
    const float* W  = (const float*)d_in[2];
    const float* b  = (const float*)d_in[3];
    const int n = in_sizes[0] / D_IN;   // 100000
    const int E = in_sizes[1] / 2;      // 3200000
    const int* row = ei;
    const int* col = ei + E;

    // workspace: h 12.8MB | pk 12.8MB | dinv 0.4MB | stot/sstart/gcur ~12KB
    char* basep = (char*)d_ws;
    size_t off = 0;
    auto alloc = [&](size_t bytes) { char* p = basep + off; off += (bytes + 63) & ~(size_t)63; return p; };
    unsigned short* h      = (unsigned short*)alloc((size_t)n * D_OUT * 2);
    u32*            pk     = (u32*)alloc((size_t)E * 4);
    float*          dinv   = (float*)alloc((size_t)n * 4);
    u32*            stot   = (u32*)alloc((size_t)NS * 4);
    u32*            sstart = (u32*)alloc((size_t)(NS + 1) * 4);
    u32*            gcur   = (u32*)alloc((size_t)NS * 4);

    const int NSW = (n + RPS - 1) / RPS;        // 782 active slices
    const int NPB = 256;                        // partition blocks
    const int CH  = (E + NPB - 1) / NPB;        // 12500 edges per block

    hipMemsetAsync(stot, 0, (size_t)NS * 4, stream);
    k_hist<<<512, 256, 0, stream>>>(row, stot, E);
    k_scan1024<<<1, 1024, 0, stream>>>(stot, sstart, gcur, E);
    k_part<<<NPB, 512, 0, stream>>>(row, col, gcur, pk, E, CH);
    k_deg<<<NSW, 256, 0, stream>>>(pk, sstart, dinv, n);
    k_gemm<<<2048, 256, 0, stream>>>(x, W, dinv, h, n);
    k_aggr<<<NSW, 512, 0, stream>>>(h, pk, sstart, dinv, b, (float*)d_out, n);
}

// Round 9
// 221.775 us; speedup vs baseline: 5.9092x; 1.0443x over previous
//
#include <hip/hip_runtime.h>

#define D_IN 128
#define D_OUT 64
#define RSH 7           // rows per slice = 128 (power of 2): slice = row >> 7
#define RPS 128
#define NS 1024         // slice array bound (782 used for n=100k)
#define ACH 5120        // edges per k_aggr chunk (> max slice size ~4300)
#define REG 10          // ACH / 512 staging registers
#define CSHIFT 17
#define CMASK 0x1FFFFu  // 17-bit col (n < 131072); rowLocal (7b) in bits 17..23

typedef unsigned int u32;

// --- bf16 helpers ----------------------------------------------------------
__device__ inline float u2f(u32 u) {
    union { u32 i; float f; } v; v.i = u; return v.f;
}
__device__ inline float bf2f(unsigned short u) { return u2f(((u32)u) << 16); }
__device__ inline unsigned short f2bf(float f) {
    union { float f; u32 i; } v; v.f = f;
    u32 r = v.i + 0x7fffu + ((v.i >> 16) & 1u);
    return (unsigned short)(r >> 16);
}

// ---------------------------------------------------------------------------
// K1: global per-slice totals (LDS hist + tiny global atomics).
// ---------------------------------------------------------------------------
__global__ __launch_bounds__(256) void k_hist(
    const int* __restrict__ row, u32* __restrict__ stot, int E) {
    __shared__ u32 cnt[NS];
    for (int t = threadIdx.x; t < NS; t += 256) cnt[t] = 0;
    __syncthreads();
    const int stride = gridDim.x * 256;
    for (int e = blockIdx.x * 256 + threadIdx.x; e < E; e += stride)
        atomicAdd(&cnt[(u32)__builtin_nontemporal_load(&row[e]) >> RSH], 1u);
    __syncthreads();
    for (int t = threadIdx.x; t < NS; t += 256) {
        u32 c = cnt[t];
        if (c) atomicAdd(&stot[t], c);
    }
}

// ---------------------------------------------------------------------------
// K2: exclusive scan of stot[1024] -> sstart[1025]; init gcur = sstart.
// ---------------------------------------------------------------------------
__global__ __launch_bounds__(1024) void k_scan1024(
    const u32* __restrict__ stot, u32* __restrict__ sstart,
    u32* __restrict__ gcur, int E) {
    __shared__ u32 tmp[1024];
    const int t = threadIdx.x;
    u32 v = stot[t];
    tmp[t] = v;
    __syncthreads();
    for (int off = 1; off < 1024; off <<= 1) {
        u32 u = (t >= off) ? tmp[t - off] : 0;
        __syncthreads();
        tmp[t] += u;
        __syncthreads();
    }
    u32 ex = tmp[t] - v;
    sstart[t] = ex;
    gcur[t] = ex;
    if (t == 1023) sstart[1024] = (u32)E;
}

// ---------------------------------------------------------------------------
// K3: partition, direct-scatter with dense per-(block,slice) runs (proven:
//     dense ~16-word runs assemble in L2, ~2x write amplification).
// ---------------------------------------------------------------------------
__global__ __launch_bounds__(512) void k_part(
    const int* __restrict__ row, const int* __restrict__ col,
    u32* __restrict__ gcur, u32* __restrict__ pk, int E, int CH) {
    __shared__ u32 cnt[NS];
    const int lo = blockIdx.x * CH, hi = min(E, lo + CH);
    for (int t = threadIdx.x; t < NS; t += 512) cnt[t] = 0;
    __syncthreads();
    for (int e = lo + threadIdx.x; e < hi; e += 512)
        atomicAdd(&cnt[(u32)__builtin_nontemporal_load(&row[e]) >> RSH], 1u);
    __syncthreads();
    for (int t = threadIdx.x; t < NS; t += 512) {
        u32 c = cnt[t];
        cnt[t] = c ? atomicAdd(&gcur[t], c) : 0u;
    }
    __syncthreads();
    for (int e = lo + threadIdx.x; e < hi; e += 512) {
        u32 rw = (u32)__builtin_nontemporal_load(&row[e]);
        u32 cw = (u32)__builtin_nontemporal_load(&col[e]);
        u32 pos = atomicAdd(&cnt[rw >> RSH], 1u);
        pk[pos] = ((rw & (RPS - 1u)) << CSHIFT) | cw;   // normal store: L2-combine
    }
}

// ---------------------------------------------------------------------------
// K4: per-slice degrees -> dinv (sequential writes).
// ---------------------------------------------------------------------------
__global__ __launch_bounds__(256) void k_deg(
    const u32* __restrict__ pk, const u32* __restrict__ sstart,
    float* __restrict__ dinv, int n) {
    __shared__ u32 cnt[RPS];
    const int s = blockIdx.x, lo = s << RSH;
    if (threadIdx.x < RPS) cnt[threadIdx.x] = 0;
    __syncthreads();
    const u32 beg = sstart[s], end = sstart[s + 1];
    for (u32 i = beg + threadIdx.x; i < end; i += 256)
        atomicAdd(&cnt[pk[i] >> CSHIFT], 1u);
    __syncthreads();
    for (int t = threadIdx.x; t < RPS && lo + t < n; t += 256)
        dinv[lo + t] = rsqrtf((float)(cnt[t] + 1u));
}

// ---------------------------------------------------------------------------
// K5: GEMM h[i][:] = bf16( dinv[i] * (x[i] @ W) ), 4 rows/wave (proven).
// ---------------------------------------------------------------------------
__global__ __launch_bounds__(256) void k_gemm(
    const float* __restrict__ x, const float* __restrict__ W,
    const float* __restrict__ dinv, unsigned short* __restrict__ h, int n) {
    __shared__ float Ws[D_IN * D_OUT];
    __shared__ float xs[4][4][D_IN];
    for (int idx = threadIdx.x; idx < D_IN * D_OUT; idx += 256)
        Ws[idx] = W[idx];
    __syncthreads();

    const int wave = threadIdx.x >> 6;
    const int lane = threadIdx.x & 63;
    float* xw = &xs[wave][0][0];

    for (int i0 = (blockIdx.x * 4 + wave) * 4; i0 < n; i0 += gridDim.x * 16) {
#pragma unroll
        for (int r = 0; r < 4; ++r) {
            int i = min(i0 + r, n - 1);
            *(float2*)&xw[r * D_IN + lane * 2] =
                *(const float2*)&x[(size_t)i * D_IN + lane * 2];
        }
        float a0 = 0.f, a1 = 0.f, a2 = 0.f, a3 = 0.f;
#pragma unroll
        for (int k4 = 0; k4 < D_IN; k4 += 4) {
            float4 x0 = *(float4*)&xw[0 * D_IN + k4];
            float4 x1 = *(float4*)&xw[1 * D_IN + k4];
            float4 x2 = *(float4*)&xw[2 * D_IN + k4];
            float4 x3 = *(float4*)&xw[3 * D_IN + k4];
#pragma unroll
            for (int u = 0; u < 4; ++u) {
                float wv = Ws[(k4 + u) * D_OUT + lane];
                a0 = fmaf((&x0.x)[u], wv, a0);
                a1 = fmaf((&x1.x)[u], wv, a1);
                a2 = fmaf((&x2.x)[u], wv, a2);
                a3 = fmaf((&x3.x)[u], wv, a3);
            }
        }
        int nr = min(4, n - i0);
        if (nr == 4) {
            h[(size_t)(i0 + 0) * D_OUT + lane] = f2bf(dinv[i0 + 0] * a0);
            h[(size_t)(i0 + 1) * D_OUT + lane] = f2bf(dinv[i0 + 1] * a1);
            h[(size_t)(i0 + 2) * D_OUT + lane] = f2bf(dinv[i0 + 2] * a2);
            h[(size_t)(i0 + 3) * D_OUT + lane] = f2bf(dinv[i0 + 3] * a3);
        } else {
            for (int r = 0; r < nr; ++r) {
                float a = (r == 0) ? a0 : (r == 1) ? a1 : (r == 2) ? a2 : a3;
                h[(size_t)(i0 + r) * D_OUT + lane] = f2bf(dinv[i0 + r] * a);
            }
        }
    }
}

// ---------------------------------------------------------------------------
// K6: aggregation, one WG (8 waves) per 128-row slice.
//     v3: pk register-staged (ONE global read), single-wave shfl scan
//     (no barrier storm), 16-deep gather ILP per half-wave.
// ---------------------------------------------------------------------------
__global__ __launch_bounds__(512, 4) void k_aggr(
    const unsigned short* __restrict__ h, const u32* __restrict__ pk,
    const u32* __restrict__ sstart, const float* __restrict__ dinv,
    const float* __restrict__ bias, float* __restrict__ out, int n) {
    __shared__ u32 cnt[RPS], eptr[RPS], cur[RPS];
    __shared__ u32 cols[ACH];   // row-sorted cols (20 KB)
    const int s = blockIdx.x, lo = s << RSH;
    const int rows = min(RPS, n - lo);
    const int tid = threadIdx.x;
    const int wave = tid >> 6, lane = tid & 63;
    const int half = lane >> 5, l31 = lane & 31;
    const u32* hp = (const u32*)h;

    float ax[16], ay[16];
#pragma unroll
    for (int k = 0; k < 16; ++k) { ax[k] = 0.f; ay[k] = 0.f; }

    const u32 beg = sstart[s], end = sstart[s + 1];
    for (u32 cb = beg; cb < end; cb += ACH) {
        const u32 ce = min(end, cb + (u32)ACH);
        const int m = (int)(ce - cb);
        // --- stage pk into registers (single global pass) ---
        u32 w[REG];
#pragma unroll
        for (int k = 0; k < REG; ++k) {
            int i = tid + k * 512;
            if (i < m) w[k] = __builtin_nontemporal_load(&pk[cb + i]);
        }
        if (tid < RPS) cnt[tid] = 0;
        __syncthreads();
#pragma unroll
        for (int k = 0; k < REG; ++k)
            if (tid + k * 512 < m) atomicAdd(&cnt[w[k] >> CSHIFT], 1u);
        __syncthreads();
        // --- single-wave exclusive scan of cnt[128] (lane owns 2 slots) ---
        if (tid < 64) {
            u32 c0 = cnt[2 * tid], c1 = cnt[2 * tid + 1];
            u32 sv = c0 + c1;
#pragma unroll
            for (int d = 1; d < 64; d <<= 1) {
                u32 t = __shfl_up(sv, d);
                if (tid >= d) sv += t;
            }
            u32 ex = sv - (c0 + c1);          // exclusive prefix
            eptr[2 * tid] = ex;     cur[2 * tid] = ex;
            eptr[2 * tid + 1] = ex + c0; cur[2 * tid + 1] = ex + c0;
        }
        __syncthreads();
        // --- scatter cols by local row (from registers) ---
#pragma unroll
        for (int k = 0; k < REG; ++k)
            if (tid + k * 512 < m) {
                u32 pos = atomicAdd(&cur[w[k] >> CSHIFT], 1u);
                cols[pos] = w[k] & CMASK;
            }
        __syncthreads();
        // --- pull with 16-deep ILP: rows q = wave + 8k ---
#pragma unroll
        for (int k = 0; k < 16; ++k) {
            int q = wave + 8 * k;
            if (q < rows) {
                const int b1 = (int)eptr[q] + (int)cnt[q];
                int t = (int)eptr[q] + half;
                for (; t + 30 < b1; t += 32) {
                    u32 c[16], u[16];
#pragma unroll
                    for (int j = 0; j < 16; ++j) c[j] = cols[t + 2 * j];
#pragma unroll
                    for (int j = 0; j < 16; ++j) u[j] = hp[(size_t)c[j] * 32 + l31];
#pragma unroll
                    for (int j = 0; j < 16; ++j) {
                        ax[k] += u2f(u[j] << 16);
                        ay[k] += u2f(u[j] & 0xffff0000u);
                    }
                }
                for (; t + 14 < b1; t += 16) {
                    u32 c[8], u[8];
#pragma unroll
                    for (int j = 0; j < 8; ++j) c[j] = cols[t + 2 * j];
#pragma unroll
                    for (int j = 0; j < 8; ++j) u[j] = hp[(size_t)c[j] * 32 + l31];
#pragma unroll
                    for (int j = 0; j < 8; ++j) {
                        ax[k] += u2f(u[j] << 16);
                        ay[k] += u2f(u[j] & 0xffff0000u);
                    }
                }
                for (; t + 6 < b1; t += 8) {
                    u32 c[4], u[4];
#pragma unroll
                    for (int j = 0; j < 4; ++j) c[j] = cols[t + 2 * j];
#pragma unroll
                    for (int j = 0; j < 4; ++j) u[j] = hp[(size_t)c[j] * 32 + l31];
#pragma unroll
                    for (int j = 0; j < 4; ++j) {
                        ax[k] += u2f(u[j] << 16);
                        ay[k] += u2f(u[j] & 0xffff0000u);
                    }
                }
                for (; t < b1; t += 2) {
                    u32 c = cols[t];
                    u32 u = hp[(size_t)c * 32 + l31];
                    ax[k] += u2f(u << 16); ay[k] += u2f(u & 0xffff0000u);
                }
            }
        }
        __syncthreads();
    }
    // combine halves + self term + finalize
#pragma unroll
    for (int k = 0; k < 16; ++k) {
        int q = wave + 8 * k;
        if (q >= rows) continue;
        float a_ = ax[k] + __shfl_xor(ax[k], 32);
        float b_ = ay[k] + __shfl_xor(ay[k], 32);
        int i = lo + q;
        u32 us = hp[(size_t)i * 32 + l31];
        a_ += u2f(us << 16);
        b_ += u2f(us & 0xffff0000u);
        float d = dinv[i];
        float2 bb = *(const float2*)&bias[l31 * 2];
        float2 r;
        r.x = fmaxf(fmaf(d, a_, bb.x), 0.f);
        r.y = fmaxf(fmaf(d, b_, bb.y), 0.f);
        if (half == 0)
            *(float2*)&out[(size_t)i * D_OUT + l31 * 2] = r;
    }
}

extern "C" void kernel_launch(void* const* d_in, const int* in_sizes, int n_in,
                              void* d_out, int out_size, void* d_ws, size_t ws_size,
                              hipStream_t stream) {
    const float* x  = (const float*)d_in[0];
    const int*   ei = (const int*)d_in[1];   // [2][E] int32: row=targets, col=sources
    const float* W  = (const float*)d_in[2];
    const float* b  = (const float*)d_in[3];
    const int n = in_sizes[0] / D_IN;   // 100000
    const int E = in_sizes[1] / 2;      // 3200000
    const int* row = ei;
    const int* col = ei + E;

    // workspace: h 12.8MB | pk 12.8MB | dinv 0.4MB | stot/sstart/gcur ~12KB
    char* basep = (char*)d_ws;
    size_t off = 0;
    auto alloc = [&](size_t bytes) { char* p = basep + off; off += (bytes + 63) & ~(size_t)63; return p; };
    unsigned short* h      = (unsigned short*)alloc((size_t)n * D_OUT * 2);
    u32*            pk     = (u32*)alloc((size_t)E * 4);
    float*          dinv   = (float*)alloc((size_t)n * 4);
    u32*            stot   = (u32*)alloc((size_t)NS * 4);
    u32*            sstart = (u32*)alloc((size_t)(NS + 1) * 4);
    u32*            gcur   = (u32*)alloc((size_t)NS * 4);

    const int NSW = (n + RPS - 1) / RPS;        // 782 active slices
    const int NPB = 256;                        // partition blocks
    const int CH  = (E + NPB - 1) / NPB;        // 12500 edges per block

    hipMemsetAsync(stot, 0, (size_t)NS * 4, stream);
    k_hist<<<512, 256, 0, stream>>>(row, stot, E);
    k_scan1024<<<1, 1024, 0, stream>>>(stot, sstart, gcur, E);
    k_part<<<NPB, 512, 0, stream>>>(row, col, gcur, pk, E, CH);
    k_deg<<<NSW, 256, 0, stream>>>(pk, sstart, dinv, n);
    k_gemm<<<2048, 256, 0, stream>>>(x, W, dinv, h, n);
    k_aggr<<<NSW, 512, 0, stream>>>(h, pk, sstart, dinv, b, (float*)d_out, n);
}

// Round 10
// 196.709 us; speedup vs baseline: 6.6622x; 1.1274x over previous
//
#include <hip/hip_runtime.h>

#define D_IN 128
#define D_OUT 64
#define RSH 7           // rows per slice = 128: slice = row >> 7
#define RPS 128
#define NS 1024         // slice array bound (782 used for n=100k)
#define ACH 5120        // edges per k_aggr chunk (> max slice size ~4300)
#define REG 10          // ACH / 512 staging registers
#define CSHIFT 17
#define CMASK 0x1FFFFu  // 17-bit col (n < 131072); rowLocal (7b) in bits 17..23

typedef unsigned int u32;
typedef __attribute__((ext_vector_type(8))) short bf16x8;
typedef __attribute__((ext_vector_type(4))) float f32x4;

// --- bf16 helpers (RNE) ----------------------------------------------------
__device__ inline float u2f(u32 u) {
    union { u32 i; float f; } v; v.i = u; return v.f;
}
__device__ inline unsigned short f2bf(float f) {
    union { float f; u32 i; } v; v.f = f;
    u32 r = v.i + 0x7fffu + ((v.i >> 16) & 1u);
    return (unsigned short)(r >> 16);
}

// ---------------------------------------------------------------------------
// K1: global per-slice totals (LDS hist + tiny global atomics).
// ---------------------------------------------------------------------------
__global__ __launch_bounds__(256) void k_hist(
    const int* __restrict__ row, u32* __restrict__ stot, int E) {
    __shared__ u32 cnt[NS];
    for (int t = threadIdx.x; t < NS; t += 256) cnt[t] = 0;
    __syncthreads();
    const int stride = gridDim.x * 256;
    for (int e = blockIdx.x * 256 + threadIdx.x; e < E; e += stride)
        atomicAdd(&cnt[(u32)__builtin_nontemporal_load(&row[e]) >> RSH], 1u);
    __syncthreads();
    for (int t = threadIdx.x; t < NS; t += 256) {
        u32 c = cnt[t];
        if (c) atomicAdd(&stot[t], c);
    }
}

// ---------------------------------------------------------------------------
// K2: exclusive scan of stot[1024] -> sstart[1025]; init gcur = sstart.
// ---------------------------------------------------------------------------
__global__ __launch_bounds__(1024) void k_scan1024(
    const u32* __restrict__ stot, u32* __restrict__ sstart,
    u32* __restrict__ gcur, int E) {
    __shared__ u32 tmp[1024];
    const int t = threadIdx.x;
    u32 v = stot[t];
    tmp[t] = v;
    __syncthreads();
    for (int off = 1; off < 1024; off <<= 1) {
        u32 u = (t >= off) ? tmp[t - off] : 0;
        __syncthreads();
        tmp[t] += u;
        __syncthreads();
    }
    u32 ex = tmp[t] - v;
    sstart[t] = ex;
    gcur[t] = ex;
    if (t == 1023) sstart[1024] = (u32)E;
}

// ---------------------------------------------------------------------------
// K3: partition, direct-scatter with dense per-(block,slice) runs (proven).
// ---------------------------------------------------------------------------
__global__ __launch_bounds__(512) void k_part(
    const int* __restrict__ row, const int* __restrict__ col,
    u32* __restrict__ gcur, u32* __restrict__ pk, int E, int CH) {
    __shared__ u32 cnt[NS];
    const int lo = blockIdx.x * CH, hi = min(E, lo + CH);
    for (int t = threadIdx.x; t < NS; t += 512) cnt[t] = 0;
    __syncthreads();
    for (int e = lo + threadIdx.x; e < hi; e += 512)
        atomicAdd(&cnt[(u32)__builtin_nontemporal_load(&row[e]) >> RSH], 1u);
    __syncthreads();
    for (int t = threadIdx.x; t < NS; t += 512) {
        u32 c = cnt[t];
        cnt[t] = c ? atomicAdd(&gcur[t], c) : 0u;
    }
    __syncthreads();
    for (int e = lo + threadIdx.x; e < hi; e += 512) {
        u32 rw = (u32)__builtin_nontemporal_load(&row[e]);
        u32 cw = (u32)__builtin_nontemporal_load(&col[e]);
        u32 pos = atomicAdd(&cnt[rw >> RSH], 1u);
        pk[pos] = ((rw & (RPS - 1u)) << CSHIFT) | cw;
    }
}

// ---------------------------------------------------------------------------
// K4: per-slice degrees -> dinv (sequential writes).
// ---------------------------------------------------------------------------
__global__ __launch_bounds__(256) void k_deg(
    const u32* __restrict__ pk, const u32* __restrict__ sstart,
    float* __restrict__ dinv, int n) {
    __shared__ u32 cnt[RPS];
    const int s = blockIdx.x, lo = s << RSH;
    if (threadIdx.x < RPS) cnt[threadIdx.x] = 0;
    __syncthreads();
    const u32 beg = sstart[s], end = sstart[s + 1];
    for (u32 i = beg + threadIdx.x; i < end; i += 256)
        atomicAdd(&cnt[pk[i] >> CSHIFT], 1u);
    __syncthreads();
    for (int t = threadIdx.x; t < RPS && lo + t < n; t += 256)
        dinv[lo + t] = rsqrtf((float)(cnt[t] + 1u));
}

// ---------------------------------------------------------------------------
// K5: MFMA GEMM. One wave per 16-row tile: h[i][:] = bf16(dinv[i]*(x[i]@W)).
//     A-frag (16x32): lane l -> row = l&15, k = (l>>4)*8 + j
//     B-frag (32x16): lane l -> col = l&15, k = (l>>4)*8 + j
//     D      (16x16): lane l -> col = l&15, row = (l>>4)*4 + reg   [m89]
//     W staged to LDS once, held as 16 reg B-frags (bf16).
// ---------------------------------------------------------------------------
__global__ __launch_bounds__(256, 4) void k_gemm(
    const float* __restrict__ x, const float* __restrict__ W,
    const float* __restrict__ dinv, unsigned short* __restrict__ h, int n) {
    __shared__ float Wl[D_IN * D_OUT];   // 32 KB
    for (int idx = threadIdx.x; idx < D_IN * D_OUT; idx += 256)
        Wl[idx] = W[idx];
    __syncthreads();

    const int lane = threadIdx.x & 63;
    const int wave = threadIdx.x >> 6;
    const int m = lane & 15, kg = lane >> 4;   // kg = 0..3

    // B-fragments, once per wave: bfr[kb][nb]
    bf16x8 bfr[4][4];
#pragma unroll
    for (int kb = 0; kb < 4; ++kb)
#pragma unroll
        for (int nb = 0; nb < 4; ++nb) {
            bf16x8 f;
#pragma unroll
            for (int j = 0; j < 8; ++j)
                f[j] = (short)f2bf(Wl[(kb * 32 + kg * 8 + j) * D_OUT + nb * 16 + m]);
            bfr[kb][nb] = f;
        }

    const int ntile = (n + 15) >> 4;
    for (int tile = blockIdx.x * 4 + wave; tile < ntile; tile += gridDim.x * 4) {
        const int i0 = tile << 4;
        const int arow = min(i0 + m, n - 1);
        const float* xr = &x[(size_t)arow * D_IN + kg * 8];

        f32x4 acc[4];
#pragma unroll
        for (int nb = 0; nb < 4; ++nb) acc[nb] = (f32x4){0.f, 0.f, 0.f, 0.f};

#pragma unroll
        for (int kb = 0; kb < 4; ++kb) {
            float4 xa = *(const float4*)(xr + kb * 32);
            float4 xb = *(const float4*)(xr + kb * 32 + 4);
            bf16x8 af;
            af[0] = (short)f2bf(xa.x); af[1] = (short)f2bf(xa.y);
            af[2] = (short)f2bf(xa.z); af[3] = (short)f2bf(xa.w);
            af[4] = (short)f2bf(xb.x); af[5] = (short)f2bf(xb.y);
            af[6] = (short)f2bf(xb.z); af[7] = (short)f2bf(xb.w);
#pragma unroll
            for (int nb = 0; nb < 4; ++nb)
                acc[nb] = __builtin_amdgcn_mfma_f32_16x16x32_bf16(
                    af, bfr[kb][nb], acc[nb], 0, 0, 0);
        }
        // epilogue: lane writes rows i0 + kg*4 + i, cols nb*16 + m
#pragma unroll
        for (int i = 0; i < 4; ++i) {
            int r = i0 + kg * 4 + i;
            if (r < n) {
                float d = dinv[r];
#pragma unroll
                for (int nb = 0; nb < 4; ++nb)
                    h[(size_t)r * D_OUT + nb * 16 + m] = f2bf(d * acc[nb][i]);
            }
        }
    }
}

// ---------------------------------------------------------------------------
// K6: aggregation, one WG (8 waves) per 128-row slice.
//     v4: quarter-wave gathers — lane = 16*qd + l15; each quarter (16 lanes
//     x 8B = full 128B h row) serves one edge -> 4 edges per instruction.
//     Accs: 4 feats/row/lane (l15*4..+3). Reduce via shfl_xor(16,32);
//     coalesced float4 output stores.
// ---------------------------------------------------------------------------
__global__ __launch_bounds__(512, 4) void k_aggr(
    const unsigned short* __restrict__ h, const u32* __restrict__ pk,
    const u32* __restrict__ sstart, const float* __restrict__ dinv,
    const float* __restrict__ bias, float* __restrict__ out, int n) {
    __shared__ u32 cnt[RPS], eptr[RPS], cur[RPS];
    __shared__ u32 cols[ACH];   // row-sorted cols (20 KB)
    const int s = blockIdx.x, lo = s << RSH;
    const int rows = min(RPS, n - lo);
    const int tid = threadIdx.x;
    const int wave = tid >> 6, lane = tid & 63;
    const int qd = lane >> 4, l15 = lane & 15;
    const uint2* hp2 = (const uint2*)h;   // 16 uint2 per h row

    float a0[16], a1[16], a2[16], a3[16];
#pragma unroll
    for (int k = 0; k < 16; ++k) { a0[k] = 0.f; a1[k] = 0.f; a2[k] = 0.f; a3[k] = 0.f; }

    const u32 beg = sstart[s], end = sstart[s + 1];
    for (u32 cb = beg; cb < end; cb += ACH) {
        const u32 ce = min(end, cb + (u32)ACH);
        const int m = (int)(ce - cb);
        // --- stage pk into registers (single global pass) ---
        u32 w[REG];
#pragma unroll
        for (int k = 0; k < REG; ++k) {
            int i = tid + k * 512;
            if (i < m) w[k] = __builtin_nontemporal_load(&pk[cb + i]);
        }
        if (tid < RPS) cnt[tid] = 0;
        __syncthreads();
#pragma unroll
        for (int k = 0; k < REG; ++k)
            if (tid + k * 512 < m) atomicAdd(&cnt[w[k] >> CSHIFT], 1u);
        __syncthreads();
        // --- single-wave exclusive scan of cnt[128] ---
        if (tid < 64) {
            u32 c0 = cnt[2 * tid], c1 = cnt[2 * tid + 1];
            u32 sv = c0 + c1;
#pragma unroll
            for (int d = 1; d < 64; d <<= 1) {
                u32 t = __shfl_up(sv, d);
                if (tid >= d) sv += t;
            }
            u32 ex = sv - (c0 + c1);
            eptr[2 * tid] = ex;          cur[2 * tid] = ex;
            eptr[2 * tid + 1] = ex + c0; cur[2 * tid + 1] = ex + c0;
        }
        __syncthreads();
        // --- scatter cols by local row (from registers) ---
#pragma unroll
        for (int k = 0; k < REG; ++k)
            if (tid + k * 512 < m) {
                u32 pos = atomicAdd(&cur[w[k] >> CSHIFT], 1u);
                cols[pos] = w[k] & CMASK;
            }
        __syncthreads();
        // --- quarter-wave pull: rows q = wave + 8k ---
#pragma unroll
        for (int k = 0; k < 16; ++k) {
            int q = wave + 8 * k;
            if (q < rows) {
                const int b1 = (int)eptr[q] + (int)cnt[q];
                int t = (int)eptr[q];
                // 8-deep: 32 edges in flight per wave
                for (; t + 32 <= b1; t += 32) {
                    u32 c[8]; uint2 u[8];
#pragma unroll
                    for (int j = 0; j < 8; ++j) c[j] = cols[t + 4 * j + qd];
#pragma unroll
                    for (int j = 0; j < 8; ++j) u[j] = hp2[(size_t)c[j] * 16 + l15];
#pragma unroll
                    for (int j = 0; j < 8; ++j) {
                        a0[k] += u2f(u[j].x << 16); a1[k] += u2f(u[j].x & 0xffff0000u);
                        a2[k] += u2f(u[j].y << 16); a3[k] += u2f(u[j].y & 0xffff0000u);
                    }
                }
                for (; t + 16 <= b1; t += 16) {
                    u32 c[4]; uint2 u[4];
#pragma unroll
                    for (int j = 0; j < 4; ++j) c[j] = cols[t + 4 * j + qd];
#pragma unroll
                    for (int j = 0; j < 4; ++j) u[j] = hp2[(size_t)c[j] * 16 + l15];
#pragma unroll
                    for (int j = 0; j < 4; ++j) {
                        a0[k] += u2f(u[j].x << 16); a1[k] += u2f(u[j].x & 0xffff0000u);
                        a2[k] += u2f(u[j].y << 16); a3[k] += u2f(u[j].y & 0xffff0000u);
                    }
                }
                for (; t + 4 <= b1; t += 4) {
                    u32 c = cols[t + qd];
                    uint2 u = hp2[(size_t)c * 16 + l15];
                    a0[k] += u2f(u.x << 16); a1[k] += u2f(u.x & 0xffff0000u);
                    a2[k] += u2f(u.y << 16); a3[k] += u2f(u.y & 0xffff0000u);
                }
                const int rem = b1 - t;
                if (qd < rem) {
                    u32 c = cols[t + qd];
                    uint2 u = hp2[(size_t)c * 16 + l15];
                    a0[k] += u2f(u.x << 16); a1[k] += u2f(u.x & 0xffff0000u);
                    a2[k] += u2f(u.y << 16); a3[k] += u2f(u.y & 0xffff0000u);
                }
            }
        }
        __syncthreads();
    }
    // reduce quarters + self term + finalize (coalesced float4 stores)
#pragma unroll
    for (int k = 0; k < 16; ++k) {
        int q = wave + 8 * k;
        if (q >= rows) continue;
        float r0 = a0[k], r1 = a1[k], r2 = a2[k], r3 = a3[k];
        r0 += __shfl_xor(r0, 16); r0 += __shfl_xor(r0, 32);
        r1 += __shfl_xor(r1, 16); r1 += __shfl_xor(r1, 32);
        r2 += __shfl_xor(r2, 16); r2 += __shfl_xor(r2, 32);
        r3 += __shfl_xor(r3, 16); r3 += __shfl_xor(r3, 32);
        int i = lo + q;
        uint2 us = hp2[(size_t)i * 16 + l15];
        r0 += u2f(us.x << 16); r1 += u2f(us.x & 0xffff0000u);
        r2 += u2f(us.y << 16); r3 += u2f(us.y & 0xffff0000u);
        float d = dinv[i];
        float4 bb = *(const float4*)&bias[l15 * 4];
        float4 o;
        o.x = fmaxf(fmaf(d, r0, bb.x), 0.f);
        o.y = fmaxf(fmaf(d, r1, bb.y), 0.f);
        o.z = fmaxf(fmaf(d, r2, bb.z), 0.f);
        o.w = fmaxf(fmaf(d, r3, bb.w), 0.f);
        if (qd == 0)
            *(float4*)&out[(size_t)i * D_OUT + l15 * 4] = o;
    }
}

extern "C" void kernel_launch(void* const* d_in, const int* in_sizes, int n_in,
                              void* d_out, int out_size, void* d_ws, size_t ws_size,
                              hipStream_t stream) {
    const float* x  = (const float*)d_in[0];
    const int*   ei = (const int*)d_in[1];   // [2][E] int32: row=targets, col=sources
    const float* W  = (const float*)d_in[2];
    const float* b  = (const float*)d_in[3];
    const int n = in_sizes[0] / D_IN;   // 100000
    const int E = in_sizes[1] / 2;      // 3200000
    const int* row = ei;
    const int* col = ei + E;

    // workspace: h 12.8MB | pk 12.8MB | dinv 0.4MB | stot/sstart/gcur ~12KB
    char* basep = (char*)d_ws;
    size_t off = 0;
    auto alloc = [&](size_t bytes) { char* p = basep + off; off += (bytes + 63) & ~(size_t)63; return p; };
    unsigned short* h      = (unsigned short*)alloc((size_t)n * D_OUT * 2);
    u32*            pk     = (u32*)alloc((size_t)E * 4);
    float*          dinv   = (float*)alloc((size_t)n * 4);
    u32*            stot   = (u32*)alloc((size_t)NS * 4);
    u32*            sstart = (u32*)alloc((size_t)(NS + 1) * 4);
    u32*            gcur   = (u32*)alloc((size_t)NS * 4);

    const int NSW = (n + RPS - 1) / RPS;        // 782 active slices
    const int NPB = 256;                        // partition blocks
    const int CH  = (E + NPB - 1) / NPB;        // 12500 edges per block

    hipMemsetAsync(stot, 0, (size_t)NS * 4, stream);
    k_hist<<<512, 256, 0, stream>>>(row, stot, E);
    k_scan1024<<<1, 1024, 0, stream>>>(stot, sstart, gcur, E);
    k_part<<<NPB, 512, 0, stream>>>(row, col, gcur, pk, E, CH);
    k_deg<<<NSW, 256, 0, stream>>>(pk, sstart, dinv, n);
    k_gemm<<<512, 256, 0, stream>>>(x, W, dinv, h, n);
    k_aggr<<<NSW, 512, 0, stream>>>(h, pk, sstart, dinv, b, (float*)d_out, n);
}